// Round 4
// baseline (465.563 us; speedup 1.0000x reference)
//
#include <hip/hip_runtime.h>
#include <hip/hip_bf16.h>
#include <math.h>

// ---------------------------------------------------------------------------
// Problem constants
// ---------------------------------------------------------------------------
#define NM 100000
#define ND 20000
#define NA 50000
#define EDG 300000
#define CAP 32   // max in-degree slots per movie node (Poisson(6): P(>32)~1.6e-14)

typedef __attribute__((ext_vector_type(8))) short shortx8;
typedef __attribute__((ext_vector_type(4))) float floatx4;
typedef __attribute__((ext_vector_type(4))) int intx4;

__device__ __forceinline__ float bf2f(unsigned int u) {
    return __uint_as_float(u << 16);
}
__device__ __forceinline__ unsigned short f2bf(float f) {
    unsigned int x = __float_as_uint(f);
    unsigned int r = x + 0x7fffu + ((x >> 16) & 1u);   // RNE
    return (unsigned short)(r >> 16);
}
__device__ __forceinline__ float gelu_exact(float x) {
    return 0.5f * x * (1.0f + erff(x * 0.70710678118654752f));
}

// ---------------------------------------------------------------------------
// Workspace layout (bytes) — total ~78.4 MB
// ---------------------------------------------------------------------------
static const size_t OFF_BT_Q      = 0;          // 144x256 bf16 (Wq^T composed | skip cols | zero)
static const size_t OFF_BT_KAMV_D = 73728;      // 256x128 bf16 (rows 0-127 ka, 128-255 mv)
static const size_t OFF_BT_KAMV_A = 139264;     // 256x128 bf16
static const size_t OFF_WKA_D     = 204800;     // 128x128 f32 (Wk[1]·a_rel0·p·scale)
static const size_t OFF_WVM_D     = 270336;     // 128x128 f32
static const size_t OFF_WKA_A     = 335872;     // 128x128 f32
static const size_t OFF_WVM_A     = 401408;     // 128x128 f32
static const size_t OFF_BQ        = 466944;     // 144 f32 (cols 128..143 = 0)
static const size_t OFF_B_KAMV_D  = 467520;     // 256 f32
static const size_t OFF_B_KAMV_A  = 468544;     // 256 f32
static const size_t OFF_BKA_D     = 469568;     // 128 f32
static const size_t OFF_BVM_D     = 470080;     // 128 f32
static const size_t OFF_BKA_A     = 470592;     // 128 f32
static const size_t OFF_BVM_A     = 471104;     // 128 f32
static const size_t OFF_WALS      = 471616;     // 128x8 f32 (g·Wa[0]@Wlin)
static const size_t OFF_BFIN      = 475712;     // 8 f32
static const size_t OFF_Q0        = 524288;     // NM*128 bf16   (25.6 MB)
static const size_t OFF_SKIPB     = 26124288;   // NM*8 f32      (3.2 MB)
static const size_t OFF_KAMV_D    = 29324288;   // ND*256 bf16   (10.24 MB)
static const size_t OFF_KAMV_A    = 39564288;   // NA*256 bf16   (25.6 MB)
static const size_t OFF_COUNTS    = 65164288;   // NM int32
static const size_t OFF_SLOTS     = 65564288;   // NM*CAP int32  (12.8 MB)

// ---------------------------------------------------------------------------
// K0a: fold a_rel/m_rel/p·scale into Wk/Wv (f32 inputs); epilogue tables
// ---------------------------------------------------------------------------
__global__ __launch_bounds__(256) void precompA(
    const float* __restrict__ Wk, const float* __restrict__ bk,
    const float* __restrict__ Wv, const float* __restrict__ bv,
    const float* __restrict__ Wa, const float* __restrict__ ba,
    const float* __restrict__ Wlin, const float* __restrict__ blin,
    const float* __restrict__ a_rel, const float* __restrict__ m_rel,
    const float* __restrict__ p_rel, const float* __restrict__ skip,
    const float* __restrict__ bpre,
    char* __restrict__ ws)
{
    int tid = blockIdx.x * 256 + threadIdx.x;
    if (tid < 65536) {
        // out[e][h*16+f] = sum_d Wsrc[e][h*16+d] * R[h][d][f] * sc
        int mat = tid >> 14, rem = tid & 16383;
        int e = rem >> 7, hf = rem & 127, h = hf >> 4, f = hf & 15;
        const float* Wsrc; const float* R; float sc; float* dst;
        if (mat == 0)      { Wsrc = Wk + 16384; R = a_rel;        sc = p_rel[h]     * 0.25f; dst = (float*)(ws + OFF_WKA_D); }
        else if (mat == 1) { Wsrc = Wv + 16384; R = m_rel;        sc = 1.0f;                 dst = (float*)(ws + OFF_WVM_D); }
        else if (mat == 2) { Wsrc = Wk + 32768; R = a_rel + 2048; sc = p_rel[8 + h] * 0.25f; dst = (float*)(ws + OFF_WKA_A); }
        else               { Wsrc = Wv + 32768; R = m_rel + 2048; sc = 1.0f;                 dst = (float*)(ws + OFF_WVM_A); }
        float s = 0.0f;
        for (int d = 0; d < 16; d++)
            s += Wsrc[e * 128 + h * 16 + d] * R[h * 256 + d * 16 + f];
        dst[e * 128 + hf] = s * sc;
    } else if (tid < 66048) {
        // folded bias vectors
        int idx = tid - 65536;
        int mat = idx >> 7, hf = idx & 127, h = hf >> 4, f = hf & 15;
        const float* bsrc; const float* R; float sc; float* dst;
        if (mat == 0)      { bsrc = bk + 128; R = a_rel;        sc = p_rel[h]     * 0.25f; dst = (float*)(ws + OFF_BKA_D); }
        else if (mat == 1) { bsrc = bv + 128; R = m_rel;        sc = 1.0f;                 dst = (float*)(ws + OFF_BVM_D); }
        else if (mat == 2) { bsrc = bk + 256; R = a_rel + 2048; sc = p_rel[8 + h] * 0.25f; dst = (float*)(ws + OFF_BKA_A); }
        else               { bsrc = bv + 256; R = m_rel + 2048; sc = 1.0f;                 dst = (float*)(ws + OFF_BVM_A); }
        float s = 0.0f;
        for (int d = 0; d < 16; d++)
            s += bsrc[h * 16 + d] * R[h * 256 + d * 16 + f];
        dst[hf] = s * sc;
    } else if (tid < 67072) {
        // WaLs[j][c] = g * sum_o Wa[0][j][o] * Wlin[o][c]
        int idx = tid - 66048;
        int j = idx >> 3, c = idx & 7;
        float g = 1.0f / (1.0f + __expf(-skip[0]));
        float s = 0.0f;
        for (int o = 0; o < 128; o++)
            s += Wa[j * 128 + o] * Wlin[o * 8 + c];
        ((float*)(ws + OFF_WALS))[j * 8 + c] = g * s;
    } else if (tid < 67080) {
        // bfin[c] = g*(ba@Wlin)[c] + (1-g)*(bpre0@Wlin)[c] + blin[c]
        int c = tid - 67072;
        float g = 1.0f / (1.0f + __expf(-skip[0]));
        float s1 = 0.0f, s2 = 0.0f;
        for (int o = 0; o < 128; o++) {
            s1 += ba[o]   * Wlin[o * 8 + c];
            s2 += bpre[o] * Wlin[o * 8 + c];
        }
        ((float*)(ws + OFF_BFIN))[c] = g * s1 + (1.0f - g) * s2 + blin[c];
    }
}

// ---------------------------------------------------------------------------
// K0b: compose pre-encoder into projection weights (consumes K0a outputs)
// ---------------------------------------------------------------------------
__global__ __launch_bounds__(256) void precompB(
    const float* __restrict__ Wpre_m, const float* __restrict__ Wpre_d,
    const float* __restrict__ Wpre_a, const float* __restrict__ bpre,
    const float* __restrict__ Wq, const float* __restrict__ bq,
    const float* __restrict__ Wlin, const float* __restrict__ skip,
    char* __restrict__ ws)
{
    int tid = blockIdx.x * 256 + threadIdx.x;
    const float* WKA_D = (const float*)(ws + OFF_WKA_D);
    const float* WVM_D = (const float*)(ws + OFF_WVM_D);
    const float* WKA_A = (const float*)(ws + OFF_WKA_A);
    const float* WVM_A = (const float*)(ws + OFF_WVM_A);

    if (tid < 36864) {
        // BT_Q[n][c], n in [0,144): n<128 -> composed Wq^T; 128..135 -> skip cols; rest 0
        int n = tid >> 8, c = tid & 255;
        float s = 0.0f;
        if (n < 128) {
            for (int e = 0; e < 128; e++)
                s += Wpre_m[c * 128 + e] * Wq[e * 128 + n];
        } else if (n < 136) {
            int cc = n - 128;
            float g = 1.0f / (1.0f + __expf(-skip[0]));
            for (int e = 0; e < 128; e++)
                s += Wpre_m[c * 128 + e] * Wlin[e * 8 + cc];
            s *= (1.0f - g);
        }
        ((unsigned short*)(ws + OFF_BT_Q))[n * 256 + c] = f2bf(s);
    } else if (tid < 69632) {
        int idx = tid - 36864;
        int nrow = idx >> 7, c = idx & 127;
        const float* Wf = (nrow < 128) ? WKA_D : WVM_D;
        int nc = nrow & 127;
        float s = 0.0f;
        for (int e = 0; e < 128; e++)
            s += Wpre_d[c * 128 + e] * Wf[e * 128 + nc];
        ((unsigned short*)(ws + OFF_BT_KAMV_D))[nrow * 128 + c] = f2bf(s);
    } else if (tid < 102400) {
        int idx = tid - 69632;
        int nrow = idx >> 7, c = idx & 127;
        const float* Wf = (nrow < 128) ? WKA_A : WVM_A;
        int nc = nrow & 127;
        float s = 0.0f;
        for (int e = 0; e < 128; e++)
            s += Wpre_a[c * 128 + e] * Wf[e * 128 + nc];
        ((unsigned short*)(ws + OFF_BT_KAMV_A))[nrow * 128 + c] = f2bf(s);
    } else if (tid < 102544) {
        int n = tid - 102400;   // bias for q panel (144 cols; skip cols get 0)
        float s = 0.0f;
        if (n < 128) {
            for (int e = 0; e < 128; e++)
                s += bpre[e] * Wq[e * 128 + n];
            s += bq[n];
        }
        ((float*)(ws + OFF_BQ))[n] = s;
    } else if (tid < 102800) {
        int nrow = tid - 102544;
        const float* Wf  = (nrow < 128) ? WKA_D : WVM_D;
        const float* bf_ = (nrow < 128) ? (const float*)(ws + OFF_BKA_D) : (const float*)(ws + OFF_BVM_D);
        int nc = nrow & 127;
        float s = 0.0f;
        for (int e = 0; e < 128; e++)
            s += bpre[128 + e] * Wf[e * 128 + nc];
        ((float*)(ws + OFF_B_KAMV_D))[nrow] = s + bf_[nc];
    } else if (tid < 103056) {
        int nrow = tid - 102800;
        const float* Wf  = (nrow < 128) ? WKA_A : WVM_A;
        const float* bf_ = (nrow < 128) ? (const float*)(ws + OFF_BKA_A) : (const float*)(ws + OFF_BVM_A);
        int nc = nrow & 127;
        float s = 0.0f;
        for (int e = 0; e < 128; e++)
            s += bpre[256 + e] * Wf[e * 128 + nc];
        ((float*)(ws + OFF_B_KAMV_A))[nrow] = s + bf_[nc];
    }
}

// ---------------------------------------------------------------------------
// Edge scatter: slot = src | (isActor << 20)
// ---------------------------------------------------------------------------
__global__ __launch_bounds__(256) void edge_scatter(
    const int* __restrict__ src_dm, const int* __restrict__ dst_dm,
    const int* __restrict__ src_am, const int* __restrict__ dst_am,
    int* __restrict__ counts, int* __restrict__ slots)
{
    int t = blockIdx.x * 256 + threadIdx.x;
    if (t >= 2 * EDG) return;
    int src, dst, tag;
    if (t < EDG) { src = src_dm[t];       dst = dst_dm[t];       tag = 0; }
    else         { src = src_am[t - EDG]; dst = dst_am[t - EDG]; tag = 1 << 20; }
    int pos = atomicAdd(&counts[dst], 1);
    if (pos < CAP) slots[(size_t)dst * CAP + pos] = src | tag;
}

// ---------------------------------------------------------------------------
// MFMA GEMM (q0 + skip): out[M x 144] = A[M x 256](f32->bf16 on the fly)
// @ BT^T + bias. nt==8 tile -> 8-col f32 skip partials.
// ---------------------------------------------------------------------------
#define MFMA16(a, b, c) __builtin_amdgcn_mfma_f32_16x16x32_bf16(a, b, c, 0, 0, 0)

template<int K, int NT, bool SKIP>
__global__ __launch_bounds__(256) void gemm_bt(
    const float* __restrict__ A, int M,
    const unsigned short* __restrict__ BT,
    const float* __restrict__ bias,
    unsigned short* __restrict__ outb, int ldout,
    float* __restrict__ skipb)
{
    __shared__ unsigned short blds[NT * 16 * 136];
    int tid = threadIdx.x;
    int w = tid >> 6, lane = tid & 63;
    int quad = lane >> 4, low = lane & 15;
    int rbase = blockIdx.x * 128 + w * 32;

    floatx4 acc[2][NT] = {};
    int rows[2];
    #pragma unroll
    for (int mt = 0; mt < 2; mt++) {
        int m = rbase + mt * 16 + low;
        if (m >= M) m = M - 1;          // clamp; stores guarded
        rows[mt] = m;
    }

    constexpr int HALVES = K / 128;
    for (int hfi = 0; hfi < HALVES; hfi++) {
        if (hfi) __syncthreads();
        for (int idx = tid; idx < NT * 16 * 16; idx += 256) {
            int n = idx >> 4, ch = idx & 15;
            *(intx4*)(&blds[n * 136 + ch * 8]) =
                *(const intx4*)(&BT[(size_t)n * K + hfi * 128 + ch * 8]);
        }
        __syncthreads();

        #pragma unroll
        for (int ks = 0; ks < 4; ks++) {
            int ko = hfi * 128 + ks * 32 + quad * 8;
            shortx8 afr[2];
            #pragma unroll
            for (int mt = 0; mt < 2; mt++) {
                const float* ap = A + (size_t)rows[mt] * K + ko;
                floatx4 f0 = *(const floatx4*)ap;
                floatx4 f1 = *(const floatx4*)(ap + 4);
                #pragma unroll
                for (int j = 0; j < 4; j++) {
                    afr[mt][j]     = (short)f2bf(f0[j]);
                    afr[mt][4 + j] = (short)f2bf(f1[j]);
                }
            }
            #pragma unroll
            for (int nt = 0; nt < NT; nt++) {
                shortx8 b = *(const shortx8*)(&blds[(nt * 16 + low) * 136 + ks * 32 + quad * 8]);
                acc[0][nt] = MFMA16(afr[0], b, acc[0][nt]);
                acc[1][nt] = MFMA16(afr[1], b, acc[1][nt]);
            }
        }
    }

    #pragma unroll
    for (int mt = 0; mt < 2; mt++) {
        #pragma unroll
        for (int nt = 0; nt < NT; nt++) {
            #pragma unroll
            for (int r = 0; r < 4; r++) {
                int row = rbase + mt * 16 + quad * 4 + r;
                if (row >= M) continue;
                int col = nt * 16 + low;
                float v = acc[mt][nt][r] + bias[col];
                if (SKIP && nt == 8) {
                    if (low < 8) skipb[(size_t)row * 8 + low] = v;
                } else {
                    outb[(size_t)row * ldout + col] = f2bf(v);
                }
            }
        }
    }
}

// ---------------------------------------------------------------------------
// Fused kamv GEMM: director blocks [0,157), actor [157,548). K=128, all 256
// output cols (ka|mv) per block -> A read once, B staged once (69.6 KB LDS).
// ---------------------------------------------------------------------------
__global__ __launch_bounds__(256, 2) void gemm_kamv(
    const float* __restrict__ A_d, const float* __restrict__ A_a,
    const unsigned short* __restrict__ BT_d, const unsigned short* __restrict__ BT_a,
    const float* __restrict__ bias_d, const float* __restrict__ bias_a,
    unsigned short* __restrict__ out_d, unsigned short* __restrict__ out_a)
{
    __shared__ unsigned short blds[256 * 136];   // 69632 B
    const int NBLK_D = (ND + 127) / 128;         // 157
    bool isD = (int)blockIdx.x < NBLK_D;
    const float* A            = isD ? A_d    : A_a;
    const unsigned short* BT  = isD ? BT_d   : BT_a;
    const float* bias         = isD ? bias_d : bias_a;
    unsigned short* outb      = isD ? out_d  : out_a;
    int M  = isD ? ND : NA;
    int bx = isD ? (int)blockIdx.x : (int)blockIdx.x - NBLK_D;

    int tid = threadIdx.x;
    int w = tid >> 6, lane = tid & 63;
    int quad = lane >> 4, low = lane & 15;
    int rbase = bx * 128 + w * 32;

    // stage all 256 B-rows (K=128) once
    for (int idx = tid; idx < 256 * 16; idx += 256) {
        int n = idx >> 4, ch = idx & 15;
        *(intx4*)(&blds[n * 136 + ch * 8]) =
            *(const intx4*)(&BT[(size_t)n * 128 + ch * 8]);
    }

    floatx4 acc[2][16] = {};
    int rows[2];
    #pragma unroll
    for (int mt = 0; mt < 2; mt++) {
        int m = rbase + mt * 16 + low;
        if (m >= M) m = M - 1;
        rows[mt] = m;
    }
    __syncthreads();

    #pragma unroll
    for (int ks = 0; ks < 4; ks++) {
        int ko = ks * 32 + quad * 8;
        shortx8 afr[2];
        #pragma unroll
        for (int mt = 0; mt < 2; mt++) {
            const float* ap = A + (size_t)rows[mt] * 128 + ko;
            floatx4 f0 = *(const floatx4*)ap;
            floatx4 f1 = *(const floatx4*)(ap + 4);
            #pragma unroll
            for (int j = 0; j < 4; j++) {
                afr[mt][j]     = (short)f2bf(f0[j]);
                afr[mt][4 + j] = (short)f2bf(f1[j]);
            }
        }
        #pragma unroll
        for (int nt = 0; nt < 16; nt++) {
            shortx8 b = *(const shortx8*)(&blds[(nt * 16 + low) * 136 + ko]);
            acc[0][nt] = MFMA16(afr[0], b, acc[0][nt]);
            acc[1][nt] = MFMA16(afr[1], b, acc[1][nt]);
        }
    }

    #pragma unroll
    for (int mt = 0; mt < 2; mt++) {
        #pragma unroll
        for (int nt = 0; nt < 16; nt++) {
            #pragma unroll
            for (int r = 0; r < 4; r++) {
                int row = rbase + mt * 16 + quad * 4 + r;
                if (row >= M) continue;
                int col = nt * 16 + low;
                outb[(size_t)row * 256 + col] = f2bf(acc[mt][nt][r] + bias[col]);
            }
        }
    }
}

// ---------------------------------------------------------------------------
// Aggregation: one wave per movie node, 4-deep edge prefetch. 64 lanes =
// 8 heads x 8 sublanes, 2 dims/lane. Softmax w/o max-sub (alpha small,
// expf clamped). Fused gelu + g·(Wa@Wlin) + skip partials + bias.
// ---------------------------------------------------------------------------
__global__ __launch_bounds__(256) void agg_kernel(
    const unsigned short* __restrict__ q0,
    const unsigned short* __restrict__ kamv_d,
    const unsigned short* __restrict__ kamv_a,
    const int* __restrict__ counts, const int* __restrict__ slots,
    const float* __restrict__ skipb,
    const float* __restrict__ WaLs, const float* __restrict__ bfin,
    float* __restrict__ out)
{
    int n = blockIdx.x * 4 + (threadIdx.x >> 6);
    int lane = threadIdx.x & 63;
    int col = (lane >> 3) * 16 + (lane & 7) * 2;

    unsigned int qu = *(const unsigned int*)(q0 + (size_t)n * 128 + col);
    float qa = bf2f(qu & 0xffffu), qb = bf2f(qu >> 16);

    int cnt = counts[n];
    cnt = (cnt < 0) ? 0 : (cnt > CAP ? CAP : cnt);
    int myslot = (lane < CAP) ? slots[(size_t)n * CAP + lane] : 0;

    float acc0 = 0.0f, acc1 = 0.0f, den = 0.0f;
    // 4-deep prefetch: issue all 8 loads of a group before consuming any.
    for (int i = 0; i < cnt; i += 4) {
        unsigned int ku[4], mu[4];
        #pragma unroll
        for (int j = 0; j < 4; j++) {
            int idx = i + j;
            int ii = (idx < cnt) ? idx : 0;     // clamp: slot 0 valid (cnt>=1 here)
            int val = __shfl(myslot, ii);
            int isA = (val >> 20) & 1;
            int src = val & 0xFFFFF;
            const unsigned short* base = (isA ? kamv_a : kamv_d) + (size_t)src * 256;
            ku[j] = *(const unsigned int*)(base + col);
            mu[j] = *(const unsigned int*)(base + 128 + col);
        }
        #pragma unroll
        for (int j = 0; j < 4; j++) {
            float p = qa * bf2f(ku[j] & 0xffffu) + qb * bf2f(ku[j] >> 16);
            p += __shfl_xor(p, 1);
            p += __shfl_xor(p, 2);
            p += __shfl_xor(p, 4);
            float wgt = __expf(fminf(p, 60.0f));
            if (i + j >= cnt) wgt = 0.0f;       // mask the clamped tail
            den  += wgt;
            acc0 += wgt * bf2f(mu[j] & 0xffffu);
            acc1 += wgt * bf2f(mu[j] >> 16);
        }
    }
    float inv = 1.0f / fmaxf(den, 1e-16f);
    float u0 = gelu_exact(acc0 * inv);
    float u1 = gelu_exact(acc1 * inv);

    float part[8];
    #pragma unroll
    for (int c = 0; c < 8; c++)
        part[c] = u0 * WaLs[col * 8 + c] + u1 * WaLs[col * 8 + 8 + c];
    #pragma unroll
    for (int off = 1; off < 64; off <<= 1) {
        #pragma unroll
        for (int c = 0; c < 8; c++) part[c] += __shfl_xor(part[c], off);
    }
    if (lane == 0) {
        floatx4 s0 = *(const floatx4*)(skipb + (size_t)n * 8);
        floatx4 s1 = *(const floatx4*)(skipb + (size_t)n * 8 + 4);
        floatx4 o0, o1;
        #pragma unroll
        for (int c = 0; c < 4; c++) {
            o0[c] = part[c]     + s0[c] + bfin[c];
            o1[c] = part[4 + c] + s1[c] + bfin[4 + c];
        }
        *(floatx4*)(out + (size_t)n * 8)     = o0;
        *(floatx4*)(out + (size_t)n * 8 + 4) = o1;
    }
}

// ---------------------------------------------------------------------------
// Host launch
// ---------------------------------------------------------------------------
extern "C" void kernel_launch(void* const* d_in, const int* in_sizes, int n_in,
                              void* d_out, int out_size, void* d_ws, size_t ws_size,
                              hipStream_t stream) {
    (void)in_sizes; (void)n_in; (void)out_size; (void)ws_size;
    const float* x_movie    = (const float*)d_in[0];
    const float* x_director = (const float*)d_in[1];
    const float* x_actor    = (const float*)d_in[2];
    const int* src_dm = (const int*)d_in[3];
    const int* dst_dm = (const int*)d_in[4];
    const int* src_am = (const int*)d_in[5];
    const int* dst_am = (const int*)d_in[6];
    // d_in[7..10] dead (only the movie output feeds the classifier)
    const float* Wpre_m = (const float*)d_in[11];
    const float* Wpre_d = (const float*)d_in[12];
    const float* Wpre_a = (const float*)d_in[13];
    const float* bpre   = (const float*)d_in[14];
    const float* Wk     = (const float*)d_in[15];
    const float* bk     = (const float*)d_in[16];
    const float* Wq     = (const float*)d_in[17];
    const float* bq     = (const float*)d_in[18];
    const float* Wv     = (const float*)d_in[19];
    const float* bv     = (const float*)d_in[20];
    const float* a_rel  = (const float*)d_in[21];
    const float* m_rel  = (const float*)d_in[22];
    const float* p_rel  = (const float*)d_in[23];
    const float* skip   = (const float*)d_in[24];
    const float* Wa     = (const float*)d_in[25];
    const float* ba     = (const float*)d_in[26];
    const float* Wlin   = (const float*)d_in[27];
    const float* blin   = (const float*)d_in[28];

    char* ws = (char*)d_ws;
    float* out = (float*)d_out;

    hipMemsetAsync(ws + OFF_COUNTS, 0, NM * sizeof(int), stream);

    precompA<<<263, 256, 0, stream>>>(Wk, bk, Wv, bv, Wa, ba, Wlin, blin,
                                      a_rel, m_rel, p_rel, skip, bpre, ws);
    precompB<<<403, 256, 0, stream>>>(Wpre_m, Wpre_d, Wpre_a, bpre,
                                      Wq, bq, Wlin, skip, ws);

    edge_scatter<<<(2 * EDG + 255) / 256, 256, 0, stream>>>(
        src_dm, dst_dm, src_am, dst_am,
        (int*)(ws + OFF_COUNTS), (int*)(ws + OFF_SLOTS));

    // q0 (bf16) + skip partials (f32) from x_movie, K=256, 9 col-tiles
    gemm_bt<256, 9, true><<<(NM + 127) / 128, 256, 0, stream>>>(
        x_movie, NM, (const unsigned short*)(ws + OFF_BT_Q),
        (const float*)(ws + OFF_BQ),
        (unsigned short*)(ws + OFF_Q0), 128, (float*)(ws + OFF_SKIPB));

    // director + actor ka|mv in one launch; both panels per block
    gemm_kamv<<<(ND + 127) / 128 + (NA + 127) / 128, 256, 0, stream>>>(
        x_director, x_actor,
        (const unsigned short*)(ws + OFF_BT_KAMV_D),
        (const unsigned short*)(ws + OFF_BT_KAMV_A),
        (const float*)(ws + OFF_B_KAMV_D), (const float*)(ws + OFF_B_KAMV_A),
        (unsigned short*)(ws + OFF_KAMV_D), (unsigned short*)(ws + OFF_KAMV_A));

    agg_kernel<<<NM / 4, 256, 0, stream>>>(
        (const unsigned short*)(ws + OFF_Q0),
        (const unsigned short*)(ws + OFF_KAMV_D),
        (const unsigned short*)(ws + OFF_KAMV_A),
        (const int*)(ws + OFF_COUNTS), (const int*)(ws + OFF_SLOTS),
        (const float*)(ws + OFF_SKIPB),
        (const float*)(ws + OFF_WALS), (const float*)(ws + OFF_BFIN), out);
}

// Round 5
// 439.777 us; speedup vs baseline: 1.0586x; 1.0586x over previous
//
#include <hip/hip_runtime.h>
#include <hip/hip_bf16.h>
#include <math.h>

// ---------------------------------------------------------------------------
// Problem constants
// ---------------------------------------------------------------------------
#define NM 100000
#define ND 20000
#define NA 50000
#define EDG 300000
#define CAP 32   // max in-degree slots per movie node (Poisson(6): P(>32)~1.6e-14)

typedef __attribute__((ext_vector_type(8))) short shortx8;
typedef __attribute__((ext_vector_type(4))) float floatx4;
typedef __attribute__((ext_vector_type(4))) int intx4;

__device__ __forceinline__ float bf2f(unsigned int u) {
    return __uint_as_float(u << 16);
}
__device__ __forceinline__ unsigned short f2bf(float f) {   // RNE (precomp only)
    unsigned int x = __float_as_uint(f);
    unsigned int r = x + 0x7fffu + ((x >> 16) & 1u);
    return (unsigned short)(r >> 16);
}
__device__ __forceinline__ unsigned short f2bf_fast(float f) {  // round-half-up
    return (unsigned short)((__float_as_uint(f) + 0x8000u) >> 16);
}
// pack 2 f32 -> dword [bf16(a) | bf16(b)<<16] : 2 add + 1 v_perm
__device__ __forceinline__ unsigned int pkbf2(float a, float b) {
    return __builtin_amdgcn_perm(__float_as_uint(b) + 0x8000u,
                                 __float_as_uint(a) + 0x8000u,
                                 0x07060302u);
}
__device__ __forceinline__ float gelu_exact(float x) {
    return 0.5f * x * (1.0f + erff(x * 0.70710678118654752f));
}

// ---------------------------------------------------------------------------
// Workspace layout (bytes) — total ~78.4 MB
// ---------------------------------------------------------------------------
static const size_t OFF_BT_Q      = 0;          // 144x256 bf16 (Wq^T composed | skip cols | zero)
static const size_t OFF_BT_KAMV_D = 73728;      // 256x128 bf16 (rows 0-127 ka, 128-255 mv)
static const size_t OFF_BT_KAMV_A = 139264;     // 256x128 bf16
static const size_t OFF_WKA_D     = 204800;     // 128x128 f32
static const size_t OFF_WVM_D     = 270336;     // 128x128 f32
static const size_t OFF_WKA_A     = 335872;     // 128x128 f32
static const size_t OFF_WVM_A     = 401408;     // 128x128 f32
static const size_t OFF_BQ        = 466944;     // 144 f32
static const size_t OFF_B_KAMV_D  = 467520;     // 256 f32
static const size_t OFF_B_KAMV_A  = 468544;     // 256 f32
static const size_t OFF_BKA_D     = 469568;     // 128 f32
static const size_t OFF_BVM_D     = 470080;     // 128 f32
static const size_t OFF_BKA_A     = 470592;     // 128 f32
static const size_t OFF_BVM_A     = 471104;     // 128 f32
static const size_t OFF_WALS      = 471616;     // 128x8 f32 (g·Wa[0]@Wlin)
static const size_t OFF_BFIN      = 475712;     // 8 f32
static const size_t OFF_Q0        = 524288;     // NM*128 bf16   (25.6 MB)
static const size_t OFF_SKIPB     = 26124288;   // NM*8 f32      (3.2 MB)
static const size_t OFF_KAMV_D    = 29324288;   // ND*256 bf16   (10.24 MB)
static const size_t OFF_KAMV_A    = 39564288;   // NA*256 bf16   (25.6 MB)
static const size_t OFF_COUNTS    = 65164288;   // NM int32
static const size_t OFF_SLOTS     = 65564288;   // NM*CAP int32  (12.8 MB)
#define KAMV_A_DELTA 10240000   // OFF_KAMV_A - OFF_KAMV_D

// ---------------------------------------------------------------------------
// K0a: fold a_rel/m_rel/p·scale into Wk/Wv; epilogue tables; zero counts
// ---------------------------------------------------------------------------
__global__ __launch_bounds__(256) void precompA(
    const float* __restrict__ Wk, const float* __restrict__ bk,
    const float* __restrict__ Wv, const float* __restrict__ bv,
    const float* __restrict__ Wa, const float* __restrict__ ba,
    const float* __restrict__ Wlin, const float* __restrict__ blin,
    const float* __restrict__ a_rel, const float* __restrict__ m_rel,
    const float* __restrict__ p_rel, const float* __restrict__ skip,
    const float* __restrict__ bpre,
    char* __restrict__ ws)
{
    int tid = blockIdx.x * 256 + threadIdx.x;
    if (tid < 65536) {
        int mat = tid >> 14, rem = tid & 16383;
        int e = rem >> 7, hf = rem & 127, h = hf >> 4, f = hf & 15;
        const float* Wsrc; const float* R; float sc; float* dst;
        if (mat == 0)      { Wsrc = Wk + 16384; R = a_rel;        sc = p_rel[h]     * 0.25f; dst = (float*)(ws + OFF_WKA_D); }
        else if (mat == 1) { Wsrc = Wv + 16384; R = m_rel;        sc = 1.0f;                 dst = (float*)(ws + OFF_WVM_D); }
        else if (mat == 2) { Wsrc = Wk + 32768; R = a_rel + 2048; sc = p_rel[8 + h] * 0.25f; dst = (float*)(ws + OFF_WKA_A); }
        else               { Wsrc = Wv + 32768; R = m_rel + 2048; sc = 1.0f;                 dst = (float*)(ws + OFF_WVM_A); }
        float s = 0.0f;
        for (int d = 0; d < 16; d++)
            s += Wsrc[e * 128 + h * 16 + d] * R[h * 256 + d * 16 + f];
        dst[e * 128 + hf] = s * sc;
    } else if (tid < 66048) {
        int idx = tid - 65536;
        int mat = idx >> 7, hf = idx & 127, h = hf >> 4, f = hf & 15;
        const float* bsrc; const float* R; float sc; float* dst;
        if (mat == 0)      { bsrc = bk + 128; R = a_rel;        sc = p_rel[h]     * 0.25f; dst = (float*)(ws + OFF_BKA_D); }
        else if (mat == 1) { bsrc = bv + 128; R = m_rel;        sc = 1.0f;                 dst = (float*)(ws + OFF_BVM_D); }
        else if (mat == 2) { bsrc = bk + 256; R = a_rel + 2048; sc = p_rel[8 + h] * 0.25f; dst = (float*)(ws + OFF_BKA_A); }
        else               { bsrc = bv + 256; R = m_rel + 2048; sc = 1.0f;                 dst = (float*)(ws + OFF_BVM_A); }
        float s = 0.0f;
        for (int d = 0; d < 16; d++)
            s += bsrc[h * 16 + d] * R[h * 256 + d * 16 + f];
        dst[hf] = s * sc;
    } else if (tid < 67072) {
        // WaLs[j][c] = g * sum_o Wa[0][j][o] * Wlin[o][c]
        int idx = tid - 66048;
        int j = idx >> 3, c = idx & 7;
        float g = 1.0f / (1.0f + __expf(-skip[0]));
        float s = 0.0f;
        for (int o = 0; o < 128; o++)
            s += Wa[j * 128 + o] * Wlin[o * 8 + c];
        ((float*)(ws + OFF_WALS))[j * 8 + c] = g * s;
    } else if (tid < 67080) {
        int c = tid - 67072;
        float g = 1.0f / (1.0f + __expf(-skip[0]));
        float s1 = 0.0f, s2 = 0.0f;
        for (int o = 0; o < 128; o++) {
            s1 += ba[o]   * Wlin[o * 8 + c];
            s2 += bpre[o] * Wlin[o * 8 + c];
        }
        ((float*)(ws + OFF_BFIN))[c] = g * s1 + (1.0f - g) * s2 + blin[c];
    } else if (tid < 67080 + NM) {
        ((int*)(ws + OFF_COUNTS))[tid - 67080] = 0;   // zero edge counters
    }
}

// ---------------------------------------------------------------------------
// K0b: compose pre-encoder into projection weights (consumes K0a outputs)
// ---------------------------------------------------------------------------
__global__ __launch_bounds__(256) void precompB(
    const float* __restrict__ Wpre_m, const float* __restrict__ Wpre_d,
    const float* __restrict__ Wpre_a, const float* __restrict__ bpre,
    const float* __restrict__ Wq, const float* __restrict__ bq,
    const float* __restrict__ Wlin, const float* __restrict__ skip,
    char* __restrict__ ws)
{
    int tid = blockIdx.x * 256 + threadIdx.x;
    const float* WKA_D = (const float*)(ws + OFF_WKA_D);
    const float* WVM_D = (const float*)(ws + OFF_WVM_D);
    const float* WKA_A = (const float*)(ws + OFF_WKA_A);
    const float* WVM_A = (const float*)(ws + OFF_WVM_A);

    if (tid < 36864) {
        int n = tid >> 8, c = tid & 255;
        float s = 0.0f;
        if (n < 128) {
            for (int e = 0; e < 128; e++)
                s += Wpre_m[c * 128 + e] * Wq[e * 128 + n];
        } else if (n < 136) {
            int cc = n - 128;
            float g = 1.0f / (1.0f + __expf(-skip[0]));
            for (int e = 0; e < 128; e++)
                s += Wpre_m[c * 128 + e] * Wlin[e * 8 + cc];
            s *= (1.0f - g);
        }
        ((unsigned short*)(ws + OFF_BT_Q))[n * 256 + c] = f2bf(s);
    } else if (tid < 69632) {
        int idx = tid - 36864;
        int nrow = idx >> 7, c = idx & 127;
        const float* Wf = (nrow < 128) ? WKA_D : WVM_D;
        int nc = nrow & 127;
        float s = 0.0f;
        for (int e = 0; e < 128; e++)
            s += Wpre_d[c * 128 + e] * Wf[e * 128 + nc];
        ((unsigned short*)(ws + OFF_BT_KAMV_D))[nrow * 128 + c] = f2bf(s);
    } else if (tid < 102400) {
        int idx = tid - 69632;
        int nrow = idx >> 7, c = idx & 127;
        const float* Wf = (nrow < 128) ? WKA_A : WVM_A;
        int nc = nrow & 127;
        float s = 0.0f;
        for (int e = 0; e < 128; e++)
            s += Wpre_a[c * 128 + e] * Wf[e * 128 + nc];
        ((unsigned short*)(ws + OFF_BT_KAMV_A))[nrow * 128 + c] = f2bf(s);
    } else if (tid < 102544) {
        int n = tid - 102400;
        float s = 0.0f;
        if (n < 128) {
            for (int e = 0; e < 128; e++)
                s += bpre[e] * Wq[e * 128 + n];
            s += bq[n];
        }
        ((float*)(ws + OFF_BQ))[n] = s;
    } else if (tid < 102800) {
        int nrow = tid - 102544;
        const float* Wf  = (nrow < 128) ? WKA_D : WVM_D;
        const float* bf_ = (nrow < 128) ? (const float*)(ws + OFF_BKA_D) : (const float*)(ws + OFF_BVM_D);
        int nc = nrow & 127;
        float s = 0.0f;
        for (int e = 0; e < 128; e++)
            s += bpre[128 + e] * Wf[e * 128 + nc];
        ((float*)(ws + OFF_B_KAMV_D))[nrow] = s + bf_[nc];
    } else if (tid < 103056) {
        int nrow = tid - 102800;
        const float* Wf  = (nrow < 128) ? WKA_A : WVM_A;
        const float* bf_ = (nrow < 128) ? (const float*)(ws + OFF_BKA_A) : (const float*)(ws + OFF_BVM_A);
        int nc = nrow & 127;
        float s = 0.0f;
        for (int e = 0; e < 128; e++)
            s += bpre[256 + e] * Wf[e * 128 + nc];
        ((float*)(ws + OFF_B_KAMV_A))[nrow] = s + bf_[nc];
    }
}

// ---------------------------------------------------------------------------
// Edge scatter: slot = byte offset of source row relative to kamv_d base
// ---------------------------------------------------------------------------
__global__ __launch_bounds__(256) void edge_scatter(
    const int* __restrict__ src_dm, const int* __restrict__ dst_dm,
    const int* __restrict__ src_am, const int* __restrict__ dst_am,
    int* __restrict__ counts, int* __restrict__ slots)
{
    int t = blockIdx.x * 256 + threadIdx.x;
    if (t >= 2 * EDG) return;
    int src, dst, delta;
    if (t < EDG) { src = src_dm[t];       dst = dst_dm[t];       delta = 0; }
    else         { src = src_am[t - EDG]; dst = dst_am[t - EDG]; delta = KAMV_A_DELTA; }
    int pos = atomicAdd(&counts[dst], 1);
    if (pos < CAP) slots[(size_t)dst * CAP + pos] = src * 512 + delta;
}

// ---------------------------------------------------------------------------
// MFMA GEMM (q0 + skip): out[M x 144] = A[M x 256](f32 -> bf16 via v_perm)
// @ BT^T + bias. nt==8 tile -> 8-col f32 skip partials.
// ---------------------------------------------------------------------------
#define MFMA16(a, b, c) __builtin_amdgcn_mfma_f32_16x16x32_bf16(a, b, c, 0, 0, 0)

template<int K, int NT, bool SKIP>
__global__ __launch_bounds__(256) void gemm_bt(
    const float* __restrict__ A, int M,
    const unsigned short* __restrict__ BT,
    const float* __restrict__ bias,
    unsigned short* __restrict__ outb, int ldout,
    float* __restrict__ skipb)
{
    __shared__ unsigned short blds[NT * 16 * 136];
    int tid = threadIdx.x;
    int w = tid >> 6, lane = tid & 63;
    int quad = lane >> 4, low = lane & 15;
    int rbase = blockIdx.x * 128 + w * 32;

    floatx4 acc[2][NT] = {};
    int rows[2];
    #pragma unroll
    for (int mt = 0; mt < 2; mt++) {
        int m = rbase + mt * 16 + low;
        if (m >= M) m = M - 1;
        rows[mt] = m;
    }

    constexpr int HALVES = K / 128;
    for (int hfi = 0; hfi < HALVES; hfi++) {
        if (hfi) __syncthreads();
        for (int idx = tid; idx < NT * 16 * 16; idx += 256) {
            int n = idx >> 4, ch = idx & 15;
            *(intx4*)(&blds[n * 136 + ch * 8]) =
                *(const intx4*)(&BT[(size_t)n * K + hfi * 128 + ch * 8]);
        }
        __syncthreads();

        #pragma unroll
        for (int ks = 0; ks < 4; ks++) {
            int ko = hfi * 128 + ks * 32 + quad * 8;
            shortx8 afr[2];
            #pragma unroll
            for (int mt = 0; mt < 2; mt++) {
                const float* ap = A + (size_t)rows[mt] * K + ko;
                floatx4 f0 = *(const floatx4*)ap;
                floatx4 f1 = *(const floatx4*)(ap + 4);
                union { intx4 i4; shortx8 s8; } av;
                av.i4[0] = (int)pkbf2(f0[0], f0[1]);
                av.i4[1] = (int)pkbf2(f0[2], f0[3]);
                av.i4[2] = (int)pkbf2(f1[0], f1[1]);
                av.i4[3] = (int)pkbf2(f1[2], f1[3]);
                afr[mt] = av.s8;
            }
            #pragma unroll
            for (int nt = 0; nt < NT; nt++) {
                shortx8 b = *(const shortx8*)(&blds[(nt * 16 + low) * 136 + ks * 32 + quad * 8]);
                acc[0][nt] = MFMA16(afr[0], b, acc[0][nt]);
                acc[1][nt] = MFMA16(afr[1], b, acc[1][nt]);
            }
        }
    }

    #pragma unroll
    for (int mt = 0; mt < 2; mt++) {
        #pragma unroll
        for (int nt = 0; nt < NT; nt++) {
            #pragma unroll
            for (int r = 0; r < 4; r++) {
                int row = rbase + mt * 16 + quad * 4 + r;
                if (row >= M) continue;
                int col = nt * 16 + low;
                float v = acc[mt][nt][r] + bias[col];
                if (SKIP && nt == 8) {
                    if (low < 8) skipb[(size_t)row * 8 + low] = v;
                } else {
                    outb[(size_t)row * ldout + col] = f2bf_fast(v);
                }
            }
        }
    }
}

// ---------------------------------------------------------------------------
// Fused kamv GEMM: director blocks [0,157), actor [157,548).
// ---------------------------------------------------------------------------
__global__ __launch_bounds__(256, 2) void gemm_kamv(
    const float* __restrict__ A_d, const float* __restrict__ A_a,
    const unsigned short* __restrict__ BT_d, const unsigned short* __restrict__ BT_a,
    const float* __restrict__ bias_d, const float* __restrict__ bias_a,
    unsigned short* __restrict__ out_d, unsigned short* __restrict__ out_a)
{
    __shared__ unsigned short blds[256 * 136];   // 69632 B
    const int NBLK_D = (ND + 127) / 128;
    bool isD = (int)blockIdx.x < NBLK_D;
    const float* A            = isD ? A_d    : A_a;
    const unsigned short* BT  = isD ? BT_d   : BT_a;
    const float* bias         = isD ? bias_d : bias_a;
    unsigned short* outb      = isD ? out_d  : out_a;
    int M  = isD ? ND : NA;
    int bx = isD ? (int)blockIdx.x : (int)blockIdx.x - NBLK_D;

    int tid = threadIdx.x;
    int w = tid >> 6, lane = tid & 63;
    int quad = lane >> 4, low = lane & 15;
    int rbase = bx * 128 + w * 32;

    for (int idx = tid; idx < 256 * 16; idx += 256) {
        int n = idx >> 4, ch = idx & 15;
        *(intx4*)(&blds[n * 136 + ch * 8]) =
            *(const intx4*)(&BT[(size_t)n * 128 + ch * 8]);
    }

    floatx4 acc[2][16] = {};
    int rows[2];
    #pragma unroll
    for (int mt = 0; mt < 2; mt++) {
        int m = rbase + mt * 16 + low;
        if (m >= M) m = M - 1;
        rows[mt] = m;
    }
    __syncthreads();

    #pragma unroll
    for (int ks = 0; ks < 4; ks++) {
        int ko = ks * 32 + quad * 8;
        shortx8 afr[2];
        #pragma unroll
        for (int mt = 0; mt < 2; mt++) {
            const float* ap = A + (size_t)rows[mt] * 128 + ko;
            floatx4 f0 = *(const floatx4*)ap;
            floatx4 f1 = *(const floatx4*)(ap + 4);
            union { intx4 i4; shortx8 s8; } av;
            av.i4[0] = (int)pkbf2(f0[0], f0[1]);
            av.i4[1] = (int)pkbf2(f0[2], f0[3]);
            av.i4[2] = (int)pkbf2(f1[0], f1[1]);
            av.i4[3] = (int)pkbf2(f1[2], f1[3]);
            afr[mt] = av.s8;
        }
        #pragma unroll
        for (int nt = 0; nt < 16; nt++) {
            shortx8 b = *(const shortx8*)(&blds[(nt * 16 + low) * 136 + ko]);
            acc[0][nt] = MFMA16(afr[0], b, acc[0][nt]);
            acc[1][nt] = MFMA16(afr[1], b, acc[1][nt]);
        }
    }

    #pragma unroll
    for (int mt = 0; mt < 2; mt++) {
        #pragma unroll
        for (int nt = 0; nt < 16; nt++) {
            #pragma unroll
            for (int r = 0; r < 4; r++) {
                int row = rbase + mt * 16 + quad * 4 + r;
                if (row >= M) continue;
                int col = nt * 16 + low;
                outb[(size_t)row * 256 + col] = f2bf_fast(acc[mt][nt][r] + bias[col]);
            }
        }
    }
}

// ---------------------------------------------------------------------------
// Aggregation: 16 lanes per node, 4 nodes per wave, 16 nodes per block.
// Lane L owns dims [L*8, L*8+8). Head h = L>>1; dot reduced via 1 shfl_xor.
// Folding butterfly for the 8-col projection reduce.
// ---------------------------------------------------------------------------
__global__ __launch_bounds__(256) void agg_kernel(
    const unsigned short* __restrict__ q0,
    const char* __restrict__ kamv0,      // = ws + OFF_KAMV_D
    const int* __restrict__ counts, const int* __restrict__ slots,
    const float* __restrict__ skipb,
    const float* __restrict__ WaLs, const float* __restrict__ bfin,
    float* __restrict__ out)
{
    __shared__ float wals[1032];   // [c][j*16+L] transposed-interleaved + bfin
    for (int i = threadIdx.x; i < 1024; i += 256) {
        int c = i >> 7, rem = i & 127, j = rem >> 4, L = rem & 15;
        wals[i] = WaLs[(L * 8 + j) * 8 + c];
    }
    if (threadIdx.x < 8) wals[1024 + threadIdx.x] = bfin[threadIdx.x];
    __syncthreads();

    int lane = threadIdx.x & 63;
    int grp = lane >> 4;               // node sub-index within wave
    int L   = lane & 15;
    int n = blockIdx.x * 16 + (threadIdx.x >> 6) * 4 + grp;

    // q fragment: 8 dims at L*8 (bf16 -> f32)
    intx4 qv = *(const intx4*)(q0 + (size_t)n * 128 + L * 8);
    float qf[8];
    #pragma unroll
    for (int d = 0; d < 4; d++) {
        unsigned int u = (unsigned int)qv[d];
        qf[2 * d]     = __uint_as_float(u << 16);
        qf[2 * d + 1] = __uint_as_float(u & 0xffff0000u);
    }

    int cnt = counts[n];
    cnt = cnt < 0 ? 0 : (cnt > CAP ? CAP : cnt);
    int s0 = slots[(size_t)n * CAP + L];    // offsets for edges 0..15

    float acc[8] = {0, 0, 0, 0, 0, 0, 0, 0};
    float den = 0.0f;
    for (int i = 0; i < cnt; i++) {
        int off = __shfl(s0, (lane & 48) + (i & 15));
        if (__builtin_expect(i >= 16, 0)) off = slots[(size_t)n * CAP + i];
        const char* p = kamv0 + off;
        intx4 ku = *(const intx4*)(p + L * 16);
        intx4 mu = *(const intx4*)(p + 256 + L * 16);
        float ph = 0.0f;
        #pragma unroll
        for (int d = 0; d < 4; d++) {
            unsigned int u = (unsigned int)ku[d];
            ph += qf[2 * d]     * __uint_as_float(u << 16);
            ph += qf[2 * d + 1] * __uint_as_float(u & 0xffff0000u);
        }
        float pf = ph + __shfl_xor(ph, 1);        // full 16-dim head dot
        float wgt = __expf(fminf(pf, 60.0f));
        den += wgt;
        #pragma unroll
        for (int d = 0; d < 4; d++) {
            unsigned int u = (unsigned int)mu[d];
            acc[2 * d]     += wgt * __uint_as_float(u << 16);
            acc[2 * d + 1] += wgt * __uint_as_float(u & 0xffff0000u);
        }
    }
    float inv = 1.0f / fmaxf(den, 1e-16f);

    // gelu + 8-col projection partials (conflict-free LDS: banks j*16+L)
    float part[8] = {0, 0, 0, 0, 0, 0, 0, 0};
    #pragma unroll
    for (int j = 0; j < 8; j++) {
        float u = gelu_exact(acc[j] * inv);
        #pragma unroll
        for (int c = 0; c < 8; c++)
            part[c] += u * wals[c * 128 + j * 16 + L];
    }

    // folding butterfly reduce over 16 lanes: 8 -> 4 -> 2 -> 1, then xor 8
    bool b0 = lane & 1, b1 = lane & 2, b2 = lane & 4;
    float t1[4], t2[2], t3;
    #pragma unroll
    for (int k = 0; k < 4; k++) {
        float send = b0 ? part[k] : part[4 + k];
        float got  = __shfl_xor(send, 1);
        t1[k] = (b0 ? part[4 + k] : part[k]) + got;
    }
    #pragma unroll
    for (int k = 0; k < 2; k++) {
        float send = b1 ? t1[k] : t1[2 + k];
        float got  = __shfl_xor(send, 2);
        t2[k] = (b1 ? t1[2 + k] : t1[k]) + got;
    }
    {
        float send = b2 ? t2[0] : t2[1];
        float got  = __shfl_xor(send, 4);
        t3 = (b2 ? t2[1] : t2[0]) + got;
    }
    t3 += __shfl_xor(t3, 8);
    // lane L (<8) holds c = 4*(L&1) + 2*((L>>1)&1) + ((L>>2)&1)
    if (L < 8) {
        int c = 4 * (L & 1) + 2 * ((L >> 1) & 1) + ((L >> 2) & 1);
        out[(size_t)n * 8 + c] = t3 + skipb[(size_t)n * 8 + c] + wals[1024 + c];
    }
}

// ---------------------------------------------------------------------------
// Host launch
// ---------------------------------------------------------------------------
extern "C" void kernel_launch(void* const* d_in, const int* in_sizes, int n_in,
                              void* d_out, int out_size, void* d_ws, size_t ws_size,
                              hipStream_t stream) {
    (void)in_sizes; (void)n_in; (void)out_size; (void)ws_size;
    const float* x_movie    = (const float*)d_in[0];
    const float* x_director = (const float*)d_in[1];
    const float* x_actor    = (const float*)d_in[2];
    const int* src_dm = (const int*)d_in[3];
    const int* dst_dm = (const int*)d_in[4];
    const int* src_am = (const int*)d_in[5];
    const int* dst_am = (const int*)d_in[6];
    const float* Wpre_m = (const float*)d_in[11];
    const float* Wpre_d = (const float*)d_in[12];
    const float* Wpre_a = (const float*)d_in[13];
    const float* bpre   = (const float*)d_in[14];
    const float* Wk     = (const float*)d_in[15];
    const float* bk     = (const float*)d_in[16];
    const float* Wq     = (const float*)d_in[17];
    const float* bq     = (const float*)d_in[18];
    const float* Wv     = (const float*)d_in[19];
    const float* bv     = (const float*)d_in[20];
    const float* a_rel  = (const float*)d_in[21];
    const float* m_rel  = (const float*)d_in[22];
    const float* p_rel  = (const float*)d_in[23];
    const float* skip   = (const float*)d_in[24];
    const float* Wa     = (const float*)d_in[25];
    const float* ba     = (const float*)d_in[26];
    const float* Wlin   = (const float*)d_in[27];
    const float* blin   = (const float*)d_in[28];

    char* ws = (char*)d_ws;
    float* out = (float*)d_out;

    precompA<<<(67080 + NM + 255) / 256, 256, 0, stream>>>(
        Wk, bk, Wv, bv, Wa, ba, Wlin, blin,
        a_rel, m_rel, p_rel, skip, bpre, ws);
    precompB<<<403, 256, 0, stream>>>(Wpre_m, Wpre_d, Wpre_a, bpre,
                                      Wq, bq, Wlin, skip, ws);

    edge_scatter<<<(2 * EDG + 255) / 256, 256, 0, stream>>>(
        src_dm, dst_dm, src_am, dst_am,
        (int*)(ws + OFF_COUNTS), (int*)(ws + OFF_SLOTS));

    gemm_bt<256, 9, true><<<(NM + 127) / 128, 256, 0, stream>>>(
        x_movie, NM, (const unsigned short*)(ws + OFF_BT_Q),
        (const float*)(ws + OFF_BQ),
        (unsigned short*)(ws + OFF_Q0), 128, (float*)(ws + OFF_SKIPB));

    gemm_kamv<<<(ND + 127) / 128 + (NA + 127) / 128, 256, 0, stream>>>(
        x_director, x_actor,
        (const unsigned short*)(ws + OFF_BT_KAMV_D),
        (const unsigned short*)(ws + OFF_BT_KAMV_A),
        (const float*)(ws + OFF_B_KAMV_D), (const float*)(ws + OFF_B_KAMV_A),
        (unsigned short*)(ws + OFF_KAMV_D), (unsigned short*)(ws + OFF_KAMV_A));

    agg_kernel<<<NM / 16, 256, 0, stream>>>(
        (const unsigned short*)(ws + OFF_Q0),
        (const char*)(ws + OFF_KAMV_D),
        (const int*)(ws + OFF_COUNTS), (const int*)(ws + OFF_SLOTS),
        (const float*)(ws + OFF_SKIPB),
        (const float*)(ws + OFF_WALS), (const float*)(ws + OFF_BFIN), out);
}